// Round 4
// baseline (181.311 us; speedup 1.0000x reference)
//
#include <hip/hip_runtime.h>
#include <math.h>

#define BIGV  1.0e8f
#define PLANE (512 * 512)            // 262144
#define NTOT  (8 * PLANE)            // 2097152
#define WPR   8                      // 64-bit words per 512-bit row

// ---------------------------------------------------------------------------
// Kernel A: pack y (int32 0/1) into per-row bitmasks. mask[b][i2][w], w<8.
// Also zeroes the epilogue's done-counter (ws is poisoned before every call).
// ---------------------------------------------------------------------------
__global__ __launch_bounds__(256) void pack_mask(const int* __restrict__ y,
                                                 unsigned long long* __restrict__ mask,
                                                 unsigned int* __restrict__ counter) {
    int e = blockIdx.x * 256 + threadIdx.x;           // [0, NTOT)
    unsigned long long bal = __ballot(y[e] != 0);
    if ((threadIdx.x & 63) == 0) mask[e >> 6] = bal;
    if (e == 0) *counter = 0u;
}

// ---------------------------------------------------------------------------
// Nearest set bit distance in a 512-bit row from position i3. Words beyond
// `lim` away are pruned (any bit found is valid; missing a farther one only
// skips a non-improving candidate). Returns large sentinel if none found.
// ---------------------------------------------------------------------------
__device__ inline int row_nearest(const unsigned long long* __restrict__ row,
                                  int i3, int lim) {
    int k = i3 >> 6, b = i3 & 63;
    unsigned long long w = row[k];
    int dr = 1 << 20;
    unsigned long long mr = w & (~0ull << b);          // bits >= i3 in word k
    if (mr) {
        dr = (__ffsll((long long)mr) - 1) - b;
    } else {
        int kmax = min(7, (i3 + lim) >> 6);
        for (int k2 = k + 1; k2 <= kmax; ++k2) {
            unsigned long long ww = row[k2];
            if (ww) { dr = (k2 << 6) + (__ffsll((long long)ww) - 1) - i3; break; }
        }
    }
    int dl = 1 << 20;
    unsigned long long ml = w & (~0ull >> (63 - b));   // bits <= i3 in word k
    if (ml) {
        dl = b - (63 - __clzll((long long)ml));
    } else {
        int kmin = max(0, (i3 - lim) >> 6);
        for (int k2 = k - 1; k2 >= kmin; --k2) {
            unsigned long long ww = row[k2];
            if (ww) { dl = i3 - ((k2 << 6) + (63 - __clzll((long long)ww))); break; }
        }
    }
    return min(dl, dr);
}

// ---------------------------------------------------------------------------
// Kernel B: exact 2-D EDT of one plane from its LDS-resident bitmask.
// Block = 256 threads handles 4 rows x 512 cols (8 pixels/thread);
// grid = 8 planes x 128 blocks. LDS = 512 rows x 8 words = 32 KB.
// ---------------------------------------------------------------------------
__global__ __launch_bounds__(256) void edt2d(const unsigned long long* __restrict__ mask,
                                             float* __restrict__ D2) {
    __shared__ unsigned long long M[512 * WPR];        // 32 KB
    int plane   = blockIdx.x >> 7;
    int rowbase = (blockIdx.x & 127) << 2;
    const unsigned long long* pm = mask + plane * (512 * WPR);
    for (int t = threadIdx.x; t < 512 * WPR; t += 256) M[t] = pm[t];
    __syncthreads();

    float* out = D2 + plane * PLANE;
    #pragma unroll
    for (int p = 0; p < 8; ++p) {
        int idx = p * 256 + threadIdx.x;               // 0..2047
        int i2  = rowbase + (idx >> 9);
        int i3  = idx & 511;

        int d0   = row_nearest(&M[i2 * WPR], i3, 512);
        float f0 = (float)d0;
        float m  = fminf(BIGV, f0 * f0);

        for (int r = 1; r < 512; ++r) {
            float fr2 = (float)(r * r);
            if (fr2 >= m) break;
            int lim = (int)sqrtf(m - fr2) + 1;
            int up = i2 - r, dn = i2 + r;
            if (up < 0 && dn >= 512) break;
            if (up >= 0) {
                float fd = (float)row_nearest(&M[up * WPR], i3, lim);
                m = fminf(m, fd * fd + fr2);
            }
            if (dn < 512) {
                float fd = (float)row_nearest(&M[dn * WPR], i3, lim);
                m = fminf(m, fd * fd + fr2);
            }
        }
        out[i2 * 512 + i3] = m;                        // exact integer < 2^24
    }
}

// ---------------------------------------------------------------------------
// Kernel C: axis-0 (length 8) min-plus + sqrt + sigmoid(x)*d + deterministic
// reduction. Last-arriving block performs the final sum (fixed index order).
// ---------------------------------------------------------------------------
__device__ inline double wave_reduce_d(double v) {
    #pragma unroll
    for (int off = 32; off > 0; off >>= 1) v += __shfl_down(v, off, 64);
    return v;
}

__global__ __launch_bounds__(256) void epilogue(const float* __restrict__ D2,
                                                const float* __restrict__ x,
                                                double* __restrict__ partials,
                                                unsigned int* __restrict__ counter,
                                                float* __restrict__ out) {
    int s = blockIdx.x * 256 + threadIdx.x;            // spatial [0, PLANE)
    float v[8];
    #pragma unroll
    for (int b = 0; b < 8; ++b) v[b] = D2[b * PLANE + s];

    double acc = 0.0;
    #pragma unroll
    for (int b = 0; b < 8; ++b) {
        float m = BIGV;
        #pragma unroll
        for (int bp = 0; bp < 8; ++bp) {
            float db = (float)((b - bp) * (b - bp));
            m = fminf(m, v[bp] + db);
        }
        float xv  = x[b * PLANE + s];
        float sig = 1.0f / (1.0f + expf(-xv));
        acc += (double)(sig * sqrtf(m));
    }

    __shared__ double lds[4];
    __shared__ int is_last;
    double w = wave_reduce_d(acc);
    int lane = threadIdx.x & 63;
    int wid  = threadIdx.x >> 6;
    if (lane == 0) lds[wid] = w;
    __syncthreads();
    if (threadIdx.x == 0) {
        double t = lds[0] + lds[1] + lds[2] + lds[3];
        __hip_atomic_store(&partials[blockIdx.x], t, __ATOMIC_RELEASE,
                           __HIP_MEMORY_SCOPE_AGENT);
        unsigned int done = __hip_atomic_fetch_add(counter, 1u, __ATOMIC_ACQ_REL,
                                                   __HIP_MEMORY_SCOPE_AGENT);
        is_last = (done == gridDim.x - 1) ? 1 : 0;
    }
    __syncthreads();
    if (is_last) {
        double a = 0.0;
        for (int i = threadIdx.x; i < 1024; i += 256)
            a += __hip_atomic_load(&partials[i], __ATOMIC_ACQUIRE,
                                   __HIP_MEMORY_SCOPE_AGENT);
        double ww = wave_reduce_d(a);
        if (lane == 0) lds[wid] = ww;
        __syncthreads();
        if (threadIdx.x == 0)
            out[0] = (float)((lds[0] + lds[1] + lds[2] + lds[3]) / (double)NTOT);
    }
}

// ---------------------------------------------------------------------------
extern "C" void kernel_launch(void* const* d_in, const int* in_sizes, int n_in,
                              void* d_out, int out_size, void* d_ws, size_t ws_size,
                              hipStream_t stream) {
    const float* x = (const float*)d_in[0];
    const int*   y = (const int*)d_in[1];
    float* out = (float*)d_out;

    unsigned long long* mask = (unsigned long long*)d_ws;            // 256 KB
    float*  D2       = (float*)((char*)d_ws + (1 << 18));            // 8 MB
    double* partials = (double*)((char*)D2 + NTOT * sizeof(float));  // 8 KB
    unsigned int* counter = (unsigned int*)(partials + 1024);

    pack_mask<<<NTOT / 256, 256, 0, stream>>>(y, mask, counter);
    edt2d<<<8 * 128, 256, 0, stream>>>(mask, D2);
    epilogue<<<PLANE / 256, 256, 0, stream>>>(D2, x, partials, counter, out);
}

// Round 5
// 120.729 us; speedup vs baseline: 1.5018x; 1.5018x over previous
//
#include <hip/hip_runtime.h>
#include <math.h>

#define BIGV  1.0e8f
#define PLANE (512 * 512)            // 262144
#define NTOT  (8 * PLANE)            // 2097152
#define PROWS 640                    // 64 pad + 512 + 64 pad
#define PSTRIDE (PROWS * 512)        // floats per padded plane

// ---------------------------------------------------------------------------
// Kernel 1: 1-D DT along axis 3 (binary input) via ballot-built 512-bit line
// mask + clz/ffs nearest-set-bit. Writes h^2 (f32, exact) into a PADDED plane
// layout: row i2 lives at (64+i2); rows 0..63 and 576..639 are BIG pads.
// Blocks >= 4096 write the pads and zero the epilogue counter.
// ---------------------------------------------------------------------------
__global__ __launch_bounds__(512) void dt_axis3(const int* __restrict__ y,
                                                float* __restrict__ g1p,
                                                unsigned int* __restrict__ counter) {
    int blk = blockIdx.x;
    if (blk >= 4096) {                                 // pad writer: 1024 blocks
        int idx = (blk - 4096) * 512 + threadIdx.x;    // [0, 524288)
        int plane = idx >> 16;
        int rem   = idx & 65535;
        int r     = rem >> 9;                          // 0..127
        int c     = rem & 511;
        int row   = (r < 64) ? r : (r + 512);          // 0..63 or 576..639
        g1p[plane * PSTRIDE + row * 512 + c] = BIGV;
        if (idx == 0) *counter = 0u;
        return;
    }
    __shared__ unsigned long long words[8];
    int i = threadIdx.x;                               // position in line
    int e = blk * 512 + i;                             // y index (lines contiguous)
    unsigned long long bal = __ballot(y[e] != 0);
    int wid  = i >> 6;
    int lane = i & 63;
    if (lane == 0) words[wid] = bal;
    __syncthreads();

    int k = wid, b = lane;
    int dr = 1 << 30;
    {
        unsigned long long m0 = words[k] & (~0ull << b);
        if (m0) {
            dr = (__ffsll((long long)m0) - 1) - b;
        } else {
            #pragma unroll
            for (int k2 = 0; k2 < 8; ++k2) {
                if (k2 > k && dr == (1 << 30) && words[k2]) {
                    dr = (k2 << 6) + (__ffsll((long long)words[k2]) - 1) - i;
                }
            }
        }
    }
    int dl = 1 << 30;
    {
        unsigned long long m0 = words[k] & (~0ull >> (63 - b));
        if (m0) {
            dl = b - (63 - __clzll((long long)m0));
        } else {
            #pragma unroll
            for (int k2 = 7; k2 >= 0; --k2) {
                if (k2 < k && dl == (1 << 30) && words[k2]) {
                    dl = i - ((k2 << 6) + 63 - __clzll((long long)words[k2]));
                }
            }
        }
    }
    int d = min(dl, dr);
    float h2 = (d > 511) ? BIGV : (float)(d * d);      // exact: d*d < 2^24
    int bb = blk >> 9, i2 = blk & 511;
    g1p[bb * PSTRIDE + (64 + i2) * 512 + i] = h2;
}

// ---------------------------------------------------------------------------
// Kernel 2: 1-D squared DT along axis 2. Thread handles (b, i2, 4 cols).
// Early-exit parabola scan over padded rows: no bounds checks for r < 64.
// ---------------------------------------------------------------------------
__global__ __launch_bounds__(256) void dt_axis2(const float* __restrict__ g1p,
                                                float* __restrict__ D2) {
    int t   = blockIdx.x * 256 + threadIdx.x;          // [0, 524288)
    int b   = t >> 16;
    int rem = t & 65535;
    int i2  = rem >> 7;
    int i3  = (rem & 127) << 2;
    const float* base = g1p + b * PSTRIDE + (64 + i2) * 512 + i3;

    float4 c0 = *(const float4*)base;
    float m0 = c0.x, m1 = c0.y, m2 = c0.z, m3 = c0.w;
    float mmax = fmaxf(fmaxf(m0, m1), fmaxf(m2, m3));

    const float* up = base;
    const float* dn = base;
    int r = 1;
    for (; r < 64; ++r) {
        float fr2 = (float)(r * r);
        if (fr2 >= mmax) break;
        up -= 512; dn += 512;
        float4 a  = *(const float4*)up;
        float4 bq = *(const float4*)dn;
        m0 = fminf(m0, fminf(a.x, bq.x) + fr2);
        m1 = fminf(m1, fminf(a.y, bq.y) + fr2);
        m2 = fminf(m2, fminf(a.z, bq.z) + fr2);
        m3 = fminf(m3, fminf(a.w, bq.w) + fr2);
        mmax = fmaxf(fmaxf(m0, m1), fmaxf(m2, m3));
    }
    if (r == 64) {                                     // ultra-rare exact fallback
        for (; r < 512; ++r) {
            float fr2 = (float)(r * r);
            if (fr2 >= mmax) break;
            int upr = i2 - r, dnr = i2 + r;
            if (upr < 0 && dnr >= 512) break;
            if (upr >= 0) {
                const float4 a = *(const float4*)(g1p + b * PSTRIDE + (64 + upr) * 512 + i3);
                m0 = fminf(m0, a.x + fr2); m1 = fminf(m1, a.y + fr2);
                m2 = fminf(m2, a.z + fr2); m3 = fminf(m3, a.w + fr2);
            }
            if (dnr < 512) {
                const float4 a = *(const float4*)(g1p + b * PSTRIDE + (64 + dnr) * 512 + i3);
                m0 = fminf(m0, a.x + fr2); m1 = fminf(m1, a.y + fr2);
                m2 = fminf(m2, a.z + fr2); m3 = fminf(m3, a.w + fr2);
            }
            mmax = fmaxf(fmaxf(m0, m1), fmaxf(m2, m3));
        }
    }
    float4 outv; outv.x = m0; outv.y = m1; outv.z = m2; outv.w = m3;
    *(float4*)(D2 + b * PLANE + i2 * 512 + i3) = outv;
}

// ---------------------------------------------------------------------------
// Kernel 3: axis-0 (8x8 min-plus) + sqrt + sigmoid(x)*d + deterministic
// reduction; last-arriving block does the final fixed-order sum.
// ---------------------------------------------------------------------------
__device__ inline double wave_reduce_d(double v) {
    #pragma unroll
    for (int off = 32; off > 0; off >>= 1) v += __shfl_down(v, off, 64);
    return v;
}

__global__ __launch_bounds__(256) void epilogue(const float* __restrict__ D2,
                                                const float* __restrict__ x,
                                                double* __restrict__ partials,
                                                unsigned int* __restrict__ counter,
                                                float* __restrict__ out) {
    int s = blockIdx.x * 256 + threadIdx.x;            // spatial [0, PLANE)
    float v[8];
    #pragma unroll
    for (int b = 0; b < 8; ++b) v[b] = D2[b * PLANE + s];

    double acc = 0.0;
    #pragma unroll
    for (int b = 0; b < 8; ++b) {
        float m = BIGV;
        #pragma unroll
        for (int bp = 0; bp < 8; ++bp) {
            float db = (float)((b - bp) * (b - bp));
            m = fminf(m, v[bp] + db);
        }
        float xv  = x[b * PLANE + s];
        float sig = 1.0f / (1.0f + expf(-xv));
        acc += (double)(sig * sqrtf(m));
    }

    __shared__ double lds[4];
    __shared__ int is_last;
    double w = wave_reduce_d(acc);
    int lane = threadIdx.x & 63;
    int wid  = threadIdx.x >> 6;
    if (lane == 0) lds[wid] = w;
    __syncthreads();
    if (threadIdx.x == 0) {
        double tsum = lds[0] + lds[1] + lds[2] + lds[3];
        __hip_atomic_store(&partials[blockIdx.x], tsum, __ATOMIC_RELEASE,
                           __HIP_MEMORY_SCOPE_AGENT);
        unsigned int done = __hip_atomic_fetch_add(counter, 1u, __ATOMIC_ACQ_REL,
                                                   __HIP_MEMORY_SCOPE_AGENT);
        is_last = (done == gridDim.x - 1) ? 1 : 0;
    }
    __syncthreads();
    if (is_last) {
        double a = 0.0;
        for (int i = threadIdx.x; i < 1024; i += 256)
            a += __hip_atomic_load(&partials[i], __ATOMIC_ACQUIRE,
                                   __HIP_MEMORY_SCOPE_AGENT);
        double ww = wave_reduce_d(a);
        if (lane == 0) lds[wid] = ww;
        __syncthreads();
        if (threadIdx.x == 0)
            out[0] = (float)((lds[0] + lds[1] + lds[2] + lds[3]) / (double)NTOT);
    }
}

// ---------------------------------------------------------------------------
extern "C" void kernel_launch(void* const* d_in, const int* in_sizes, int n_in,
                              void* d_out, int out_size, void* d_ws, size_t ws_size,
                              hipStream_t stream) {
    const float* x = (const float*)d_in[0];
    const int*   y = (const int*)d_in[1];
    float* out = (float*)d_out;

    float*  g1p      = (float*)d_ws;                               // 10.5 MB padded
    float*  D2       = g1p + 8 * PSTRIDE;                          // 8 MB
    double* partials = (double*)(D2 + NTOT);                       // 8 KB
    unsigned int* counter = (unsigned int*)(partials + 1024);

    dt_axis3<<<5120, 512, 0, stream>>>(y, g1p, counter);
    dt_axis2<<<2048, 256, 0, stream>>>(g1p, D2);
    epilogue<<<PLANE / 256, 256, 0, stream>>>(D2, x, partials, counter, out);
}